// Round 12
// baseline (93.169 us; speedup 1.0000x reference)
//
#include <hip/hip_runtime.h>
#include <hip/hip_bf16.h>
#include <math.h>

#define DD 48
#define NN 512
#define TWO_D 96
#define ROWS 2048   // B*N = 4*512

typedef __attribute__((ext_vector_type(8))) short bf16x8;
typedef __attribute__((ext_vector_type(4))) float f32x4;
typedef __attribute__((ext_vector_type(2))) float f32x2;
typedef __attribute__((ext_vector_type(4))) unsigned int u32x4;

// Packed exact-erf GELU (degree-5 poly, R8/R9-verified coefficients) on float2:
// compiles to v_pk_fma_f32 / v_pk_min/max_f32 (2 elems per VALU op).
__device__ __forceinline__ f32x2 gelu_poly2(f32x2 u) {
    f32x2 lim;  lim  = 3.5777f;
    f32x2 nlim; nlim = -3.5777f;
    const f32x2 uc = __builtin_elementwise_min(__builtin_elementwise_max(u, nlim), lim);
    const f32x2 v = uc * uc;
    f32x2 c5; c5 = -1.04448e-6f;
    f32x2 c4; c4 = 4.61896e-5f;
    f32x2 c3; c3 = -8.62284e-4f;
    f32x2 c2; c2 = 9.22138e-3f;
    f32x2 c1; c1 = -6.58353e-2f;
    f32x2 c0; c0 = 3.98855e-1f;
    f32x2 E = __builtin_elementwise_fma(v, c5, c4);
    E = __builtin_elementwise_fma(v, E, c3);
    E = __builtin_elementwise_fma(v, E, c2);
    E = __builtin_elementwise_fma(v, E, c1);
    E = __builtin_elementwise_fma(v, E, c0);
    f32x2 hlf; hlf = 0.5f;
    return u * __builtin_elementwise_fma(uc, E, hlf);
}

// unpack a bf16 pair (packed in one u32) to float2 {elem_even, elem_odd}
__device__ __forceinline__ f32x2 bfpair(unsigned int w) {
    f32x2 r;
    r.x = __uint_as_float(w << 16);
    r.y = __uint_as_float(w & 0xffff0000u);
    return r;
}

// Kernel 1: blocks 0..511: A[r][t] = x_r @ W1[:48,t] + b1[t] (fp32);
//           Bb[r][t] = bf16(x_r @ W1[48:,t]); block 512: W2T[f][k] = bf16(W2[k][f])
__global__ __launch_bounds__(256) void precompute_kernel(
        const float* __restrict__ x,
        const float* __restrict__ W1,
        const float* __restrict__ b1,
        const float* __restrict__ W2,
        float* __restrict__ Aout,
        __hip_bfloat16* __restrict__ Bout,
        __hip_bfloat16* __restrict__ W2T) {
    if (blockIdx.x == ROWS / 4) {
        for (int idx = threadIdx.x; idx < DD * TWO_D; idx += 256) {
            const int f = idx / TWO_D;
            const int k = idx - f * TWO_D;
            W2T[idx] = __float2bfloat16(W2[k * DD + f]);
        }
        return;
    }
    const int wave = threadIdx.x >> 6;
    const int lane = threadIdx.x & 63;
    const int row = blockIdx.x * 4 + wave;
    __shared__ float xs[4][DD];
    if (threadIdx.x < 4 * DD)
        xs[threadIdx.x / DD][threadIdx.x % DD] = x[blockIdx.x * 4 * DD + threadIdx.x];
    __syncthreads();
    for (int t = lane; t < TWO_D; t += 64) {
        float a0 = 0.f, a1 = 0.f;
#pragma unroll 8
        for (int k = 0; k < DD; ++k) {
            const float xv = xs[wave][k];
            a0 = fmaf(xv, W1[k * TWO_D + t], a0);
            a1 = fmaf(xv, W1[(DD + k) * TWO_D + t], a1);
        }
        Aout[row * TWO_D + t] = a0 + b1[t];
        Bout[row * TWO_D + t] = __float2bfloat16(a1);
    }
}

// ---- building-block macros (textual, constant-indexed => registers, no spills)

#define LOAD_PB(PB_, PTR_)                                                      \
  { _Pragma("unroll")                                                           \
    for (int ks = 0; ks < 3; ++ks)                                              \
      PB_[ks] = *(const u32x4*)&(PTR_)[ks * 32 + q8]; }

// packed gelu + pack + 3 MFMA for one chunk; optionally prefetch next chunk
#define CHUNK_MFMA(PB_, ACC_, PF_, NPTR_)                                       \
  { _Pragma("unroll")                                                           \
    for (int ks = 0; ks < 3; ++ks) {                                            \
      const unsigned int w0 = PB_[ks].x, w1 = PB_[ks].y,                        \
                         w2 = PB_[ks].z, w3 = PB_[ks].w;                        \
      if (PF_) PB_[ks] = *(const u32x4*)&(NPTR_)[ks * 32 + q8];                 \
      const f32x2 h0 = gelu_poly2(av2[ks][0] + bfpair(w0));                     \
      const f32x2 h1 = gelu_poly2(av2[ks][1] + bfpair(w1));                     \
      const f32x2 h2 = gelu_poly2(av2[ks][2] + bfpair(w2));                     \
      const f32x2 h3 = gelu_poly2(av2[ks][3] + bfpair(w3));                     \
      union { bf16x8 v; __hip_bfloat162 h2[4]; } hf;                            \
      hf.h2[0] = __float22bfloat162_rn(make_float2(h0.x, h0.y));                \
      hf.h2[1] = __float22bfloat162_rn(make_float2(h1.x, h1.y));                \
      hf.h2[2] = __float22bfloat162_rn(make_float2(h2.x, h2.y));                \
      hf.h2[3] = __float22bfloat162_rn(make_float2(h3.x, h3.y));                \
      ACC_[0] = __builtin_amdgcn_mfma_f32_16x16x32_bf16(bfrag[0][ks], hf.v, ACC_[0], 0, 0, 0); \
      ACC_[1] = __builtin_amdgcn_mfma_f32_16x16x32_bf16(bfrag[1][ks], hf.v, ACC_[1], 0, 0, 0); \
      ACC_[2] = __builtin_amdgcn_mfma_f32_16x16x32_bf16(bfrag[2][ks], hf.v, ACC_[2], 0, 0, 0); \
    } }

// epilogue for one chunk (packed): lane holds P[f=t*16+4q+r][j=J0_+n]
#define CHUNK_EPI(J0_, I_, ACC_, L_, O_)                                        \
  { f32x2 pv[3][2];                                                             \
    f32x2 ss2; ss2 = 0.f;                                                       \
    _Pragma("unroll")                                                           \
    for (int t = 0; t < 3; ++t) {                                               \
      f32x2 a01; a01.x = ACC_[t][0]; a01.y = ACC_[t][1];                        \
      f32x2 a23; a23.x = ACC_[t][2]; a23.y = ACC_[t][3];                        \
      pv[t][0] = a01 + b2v2[t][0];                                              \
      pv[t][1] = a23 + b2v2[t][1];                                              \
      ss2 = __builtin_elementwise_fma(pv[t][0], pv[t][0], ss2);                 \
      ss2 = __builtin_elementwise_fma(pv[t][1], pv[t][1], ss2);                 \
    }                                                                           \
    float ss = ss2.x + ss2.y;                                                   \
    ss += __shfl_xor(ss, 16);                                                   \
    ss += __shfl_xor(ss, 32);                                                   \
    const int j = (J0_) + n;                                                    \
    const float ew = (j <= (I_))                                                \
        ? __builtin_amdgcn_exp2f(sqrtf(ss) * 1.44269504f) : 0.f;                \
    L_ += ew;                                                                   \
    f32x2 ew2; ew2 = ew;                                                        \
    _Pragma("unroll")                                                           \
    for (int t = 0; t < 3; ++t) {                                               \
      O_[t][0] = __builtin_elementwise_fma(ew2, pv[t][0], O_[t][0]);            \
      O_[t][1] = __builtin_elementwise_fma(ew2, pv[t][1], O_[t][1]);            \
    } }

// one row, DUAL chunk streams (c, c+4) stepping 8
#define PROCESS_ROW_DUAL(I_, ROW_, CSTART_, L_, O_)                             \
  { f32x2 av2[3][4];                                                            \
    _Pragma("unroll")                                                           \
    for (int ks = 0; ks < 3; ++ks) {                                            \
      const float4 a0 = *(const float4*)&Arow[(size_t)(ROW_)*TWO_D + ks*32 + q8];     \
      const float4 a1 = *(const float4*)&Arow[(size_t)(ROW_)*TWO_D + ks*32 + q8 + 4]; \
      av2[ks][0].x=a0.x; av2[ks][0].y=a0.y; av2[ks][1].x=a0.z; av2[ks][1].y=a0.w;     \
      av2[ks][2].x=a1.x; av2[ks][2].y=a1.y; av2[ks][3].x=a1.z; av2[ks][3].y=a1.w;     \
    }                                                                           \
    const int nch = ((I_) + 16) >> 4;                                           \
    int c = (CSTART_);                                                          \
    const __hip_bfloat16* __restrict__ Bp =                                     \
        Bbase + (size_t)((c << 4) + n) * TWO_D;                                 \
    u32x4 pbA[3], pbB[3];                                                       \
    if (c < nch) LOAD_PB(pbA, Bp);                                              \
    if (c + 4 < nch) LOAD_PB(pbB, Bp + 64 * TWO_D);                             \
    for (; c + 4 < nch; c += 8) {                                               \
      const bool pfA = (c + 8) < nch;                                           \
      const bool pfB = (c + 12) < nch;                                          \
      const __hip_bfloat16* __restrict__ BpA = Bp + 128 * TWO_D;                \
      const __hip_bfloat16* __restrict__ BpB = Bp + 192 * TWO_D;                \
      f32x4 accA[3] = {{0.f,0.f,0.f,0.f},{0.f,0.f,0.f,0.f},{0.f,0.f,0.f,0.f}};  \
      f32x4 accB[3] = {{0.f,0.f,0.f,0.f},{0.f,0.f,0.f,0.f},{0.f,0.f,0.f,0.f}};  \
      CHUNK_MFMA(pbA, accA, pfA, BpA);                                          \
      CHUNK_MFMA(pbB, accB, pfB, BpB);                                          \
      CHUNK_EPI((c << 4), I_, accA, L_, O_);                                    \
      CHUNK_EPI(((c + 4) << 4), I_, accB, L_, O_);                              \
      Bp = BpA;                                                                 \
    }                                                                           \
    if (c < nch) {                                                              \
      f32x4 accA[3] = {{0.f,0.f,0.f,0.f},{0.f,0.f,0.f,0.f},{0.f,0.f,0.f,0.f}};  \
      CHUNK_MFMA(pbA, accA, false, Bp);                                         \
      CHUNK_EPI((c << 4), I_, accA, L_, O_);                                    \
    } }

// Kernel 2: one block per (batch, row-PAIR (p, 511-p)); 33 chunks per block
// (uniform), 1024 blocks all co-resident; dual chunk streams per wave; all
// element-pair math packed (v_pk_*_f32).
__global__ __launch_bounds__(256) void pair_softmax_kernel(
        const float* __restrict__ Arow,
        const __hip_bfloat16* __restrict__ Brow,
        const __hip_bfloat16* __restrict__ W2T,
        const float* __restrict__ b2,
        float* __restrict__ out) {
    const int batch = blockIdx.x >> 8;        // 0..3
    const int pr = blockIdx.x & 255;          // 0..255
    const int iH = (NN - 1) - pr;             // 256..511
    const int iL = pr;                        // 0..255
    const int cH = (iH >> 4) + 1;             // 17..32; cH + cL = 33
    const int rowH = batch * NN + iH;
    const int rowL = batch * NN + iL;
    const __hip_bfloat16* __restrict__ Bbase = Brow + (size_t)batch * NN * TWO_D;

    const int tid = threadIdx.x;
    const int wave = tid >> 6;                // 0..3
    const int lane = tid & 63;
    const int n = lane & 15;   // j-local (C/D col); also W2T A-frag row f-local
    const int q = lane >> 4;   // quad
    const int q8 = q * 8;

    // W2T fragments (A-operand): lane holds W2T[f=t*16+n][ks*32+q8+0..7]
    bf16x8 bfrag[3][3];
#pragma unroll
    for (int t = 0; t < 3; ++t)
#pragma unroll
        for (int ks = 0; ks < 3; ++ks)
            bfrag[t][ks] = *(const bf16x8*)&W2T[(t * 16 + n) * TWO_D + ks * 32 + q8];
    // b2 pairs for this lane's C/D rows: f = t*16 + 4q + {0,1},{2,3}
    f32x2 b2v2[3][2];
#pragma unroll
    for (int t = 0; t < 3; ++t) {
        b2v2[t][0].x = b2[t * 16 + 4 * q + 0];
        b2v2[t][0].y = b2[t * 16 + 4 * q + 1];
        b2v2[t][1].x = b2[t * 16 + 4 * q + 2];
        b2v2[t][1].y = b2[t * 16 + 4 * q + 3];
    }

    float lH = 0.f, lL = 0.f;
    f32x2 oH[3][2], oL[3][2];
#pragma unroll
    for (int t = 0; t < 3; ++t)
#pragma unroll
        for (int r = 0; r < 2; ++r) { oH[t][r] = 0.f; oL[t][r] = 0.f; }

    // Heavy row: chunks c ≡ wave (mod 4)
    PROCESS_ROW_DUAL(iH, rowH, wave, lH, oH);
    // Light row: global chunk index idx = cH + c ≡ wave (mod 4)
    const int cstartL = (wave + 128 - cH) & 3;
    PROCESS_ROW_DUAL(iL, rowL, cstartL, lL, oL);

    // ---- Final reduce over n (16 lanes; q bits untouched)
#pragma unroll
    for (int d = 1; d <= 8; d <<= 1) {
        lH += __shfl_xor(lH, d);
        lL += __shfl_xor(lL, d);
#pragma unroll
        for (int t = 0; t < 3; ++t)
#pragma unroll
            for (int r = 0; r < 2; ++r) {
                oH[t][r].x += __shfl_xor(oH[t][r].x, d);
                oH[t][r].y += __shfl_xor(oH[t][r].y, d);
                oL[t][r].x += __shfl_xor(oL[t][r].x, d);
                oL[t][r].y += __shfl_xor(oL[t][r].y, d);
            }
    }
    __shared__ float lred[4][2];
    __shared__ float ored[4][2][DD];
    if (n == 0) {
#pragma unroll
        for (int t = 0; t < 3; ++t)
#pragma unroll
            for (int r = 0; r < 2; ++r) {
                ored[wave][0][t * 16 + 4 * q + 2 * r + 0] = oH[t][r].x;
                ored[wave][0][t * 16 + 4 * q + 2 * r + 1] = oH[t][r].y;
                ored[wave][1][t * 16 + 4 * q + 2 * r + 0] = oL[t][r].x;
                ored[wave][1][t * 16 + 4 * q + 2 * r + 1] = oL[t][r].y;
            }
    }
    if (lane == 0) { lred[wave][0] = lH; lred[wave][1] = lL; }
    __syncthreads();
    if (tid < 2 * DD) {
        const int sel = tid / DD;
        const int f = tid - sel * DD;
        float L = 0.f, O = 0.f;
#pragma unroll
        for (int wv = 0; wv < 4; ++wv) {
            L += lred[wv][sel];
            O += ored[wv][sel][f];
        }
        const int row = sel ? rowL : rowH;
        out[row * DD + f] = O / L;
    }
}

extern "C" void kernel_launch(void* const* d_in, const int* in_sizes, int n_in,
                              void* d_out, int out_size, void* d_ws, size_t ws_size,
                              hipStream_t stream) {
    const float* x  = (const float*)d_in[0];
    const float* W1 = (const float*)d_in[1];
    const float* b1 = (const float*)d_in[2];
    const float* W2 = (const float*)d_in[3];
    const float* b2 = (const float*)d_in[4];
    float* outp = (float*)d_out;

    float* A = (float*)d_ws;                                    // 2048*96 fp32
    __hip_bfloat16* Bb  = (__hip_bfloat16*)(A + ROWS * TWO_D);  // 2048*96 bf16
    __hip_bfloat16* W2T = Bb + ROWS * TWO_D;                    // 48*96 bf16

    precompute_kernel<<<ROWS / 4 + 1, 256, 0, stream>>>(x, W1, b1, W2, A, Bb, W2T);
    pair_softmax_kernel<<<1024, 256, 0, stream>>>(A, Bb, W2T, b2, outp);
}

// Round 13
// 92.752 us; speedup vs baseline: 1.0045x; 1.0045x over previous
//
#include <hip/hip_runtime.h>
#include <hip/hip_bf16.h>
#include <hip/hip_fp16.h>
#include <math.h>

#define DD 48
#define NN 512
#define TWO_D 96
#define ROWS 2048   // B*N = 4*512
#define W2P 104     // padded LDS row (f16) for W2T: 52 dwords, gcd(20,32)=4 -> ~2-way (free)

typedef __attribute__((ext_vector_type(8))) _Float16 f16x8;
typedef __attribute__((ext_vector_type(4))) float f32x4;
typedef __attribute__((ext_vector_type(2))) float f32x2;
typedef __attribute__((ext_vector_type(4))) unsigned int u32x4;

__device__ __forceinline__ __half2 h2cast(unsigned int u) { return __builtin_bit_cast(__half2, u); }

// Packed exact-erf GELU (deg-5 poly, R8/R9/R12-verified coefficients) on f32x2.
__device__ __forceinline__ f32x2 gelu_poly2(f32x2 u) {
    f32x2 lim;  lim  = 3.5777f;
    f32x2 nlim; nlim = -3.5777f;
    const f32x2 uc = __builtin_elementwise_min(__builtin_elementwise_max(u, nlim), lim);
    const f32x2 v = uc * uc;
    f32x2 c5; c5 = -1.04448e-6f;
    f32x2 c4; c4 = 4.61896e-5f;
    f32x2 c3; c3 = -8.62284e-4f;
    f32x2 c2; c2 = 9.22138e-3f;
    f32x2 c1; c1 = -6.58353e-2f;
    f32x2 c0; c0 = 3.98855e-1f;
    f32x2 E = __builtin_elementwise_fma(v, c5, c4);
    E = __builtin_elementwise_fma(v, E, c3);
    E = __builtin_elementwise_fma(v, E, c2);
    E = __builtin_elementwise_fma(v, E, c1);
    E = __builtin_elementwise_fma(v, E, c0);
    f32x2 hlf; hlf = 0.5f;
    return u * __builtin_elementwise_fma(uc, E, hlf);
}

// Kernel 1: blocks 0..511: A[r][t] = f16(x_r @ W1[:48,t] + b1[t]);
//           Bb[r][t] = f16(x_r @ W1[48:,t]); block 512: W2T[f][k] = f16(W2[k][f])
__global__ __launch_bounds__(256) void precompute_kernel(
        const float* __restrict__ x,
        const float* __restrict__ W1,
        const float* __restrict__ b1,
        const float* __restrict__ W2,
        __half* __restrict__ Aout,
        __half* __restrict__ Bout,
        __half* __restrict__ W2T) {
    if (blockIdx.x == ROWS / 4) {
        for (int idx = threadIdx.x; idx < DD * TWO_D; idx += 256) {
            const int f = idx / TWO_D;
            const int k = idx - f * TWO_D;
            W2T[idx] = __float2half(W2[k * DD + f]);
        }
        return;
    }
    const int wave = threadIdx.x >> 6;
    const int lane = threadIdx.x & 63;
    const int row = blockIdx.x * 4 + wave;
    __shared__ float xs[4][DD];
    if (threadIdx.x < 4 * DD)
        xs[threadIdx.x / DD][threadIdx.x % DD] = x[blockIdx.x * 4 * DD + threadIdx.x];
    __syncthreads();
    for (int t = lane; t < TWO_D; t += 64) {
        float a0 = 0.f, a1 = 0.f;
#pragma unroll 8
        for (int k = 0; k < DD; ++k) {
            const float xv = xs[wave][k];
            a0 = fmaf(xv, W1[k * TWO_D + t], a0);
            a1 = fmaf(xv, W1[(DD + k) * TWO_D + t], a1);
        }
        Aout[row * TWO_D + t] = __float2half(a0 + b1[t]);
        Bout[row * TWO_D + t] = __float2half(a1);
    }
}

// ---- macros (textual, constant-indexed => registers) ----

#define LOAD_PB(PB_, PTR_)                                                      \
  { _Pragma("unroll")                                                           \
    for (int ks = 0; ks < 3; ++ks)                                              \
      PB_[ks] = *(const u32x4*)&(PTR_)[ks * 32 + q8]; }

// one stream's gelu+pack+3 MFMA for one ks step (bf0..2 already loaded from LDS)
#define STREAM_KS(PB_, ACC_, PF_, NPTR_, KS_)                                   \
  { const u32x4 aw = avp[KS_];                                                  \
    const u32x4 bw = PB_[KS_];                                                  \
    if (PF_) PB_[KS_] = *(const u32x4*)&(NPTR_)[(KS_) * 32 + q8];               \
    const __half2 u0 = __hadd2(h2cast(aw.x), h2cast(bw.x));                     \
    const __half2 u1 = __hadd2(h2cast(aw.y), h2cast(bw.y));                     \
    const __half2 u2 = __hadd2(h2cast(aw.z), h2cast(bw.z));                     \
    const __half2 u3 = __hadd2(h2cast(aw.w), h2cast(bw.w));                     \
    f32x2 f0, f1, f2, f3;                                                       \
    { float2 t_ = __half22float2(u0); f0.x = t_.x; f0.y = t_.y; }               \
    { float2 t_ = __half22float2(u1); f1.x = t_.x; f1.y = t_.y; }               \
    { float2 t_ = __half22float2(u2); f2.x = t_.x; f2.y = t_.y; }               \
    { float2 t_ = __half22float2(u3); f3.x = t_.x; f3.y = t_.y; }               \
    const f32x2 g0 = gelu_poly2(f0);                                            \
    const f32x2 g1 = gelu_poly2(f1);                                            \
    const f32x2 g2 = gelu_poly2(f2);                                            \
    const f32x2 g3 = gelu_poly2(f3);                                            \
    union { f16x8 v; __half2 h2[4]; } hf;                                       \
    hf.h2[0] = __float22half2_rn(make_float2(g0.x, g0.y));                      \
    hf.h2[1] = __float22half2_rn(make_float2(g1.x, g1.y));                      \
    hf.h2[2] = __float22half2_rn(make_float2(g2.x, g2.y));                      \
    hf.h2[3] = __float22half2_rn(make_float2(g3.x, g3.y));                      \
    ACC_[0] = __builtin_amdgcn_mfma_f32_16x16x32_f16(bf0, hf.v, ACC_[0], 0, 0, 0); \
    ACC_[1] = __builtin_amdgcn_mfma_f32_16x16x32_f16(bf1, hf.v, ACC_[1], 0, 0, 0); \
    ACC_[2] = __builtin_amdgcn_mfma_f32_16x16x32_f16(bf2, hf.v, ACC_[2], 0, 0, 0); \
  }

// fused chunk-pair: per ks load bfrag once from LDS, run both streams
#define FUSED_KS(PBa_, ACCa_, PFa_, NPa_, DOB_, PBb_, ACCb_, PFb_, NPb_)        \
  { _Pragma("unroll")                                                           \
    for (int ksi = 0; ksi < 3; ++ksi) {                                         \
      const f16x8 bf0 = *(const f16x8*)&w2s[(0 * 16 + n) * W2P + ksi * 32 + q8];\
      const f16x8 bf1 = *(const f16x8*)&w2s[(1 * 16 + n) * W2P + ksi * 32 + q8];\
      const f16x8 bf2 = *(const f16x8*)&w2s[(2 * 16 + n) * W2P + ksi * 32 + q8];\
      STREAM_KS(PBa_, ACCa_, PFa_, NPa_, ksi);                                  \
      if (DOB_) STREAM_KS(PBb_, ACCb_, PFb_, NPb_, ksi);                        \
    } }

// epilogue for one chunk: lane holds P[f=t*16+4q+r][j=J0_+n]; b2 already in ACC
#define CHUNK_EPI(J0_, I_, ACC_, L_, O_)                                        \
  { f32x2 pv[3][2];                                                             \
    f32x2 ss2; ss2 = 0.f;                                                       \
    _Pragma("unroll")                                                           \
    for (int t = 0; t < 3; ++t) {                                               \
      pv[t][0].x = ACC_[t][0]; pv[t][0].y = ACC_[t][1];                         \
      pv[t][1].x = ACC_[t][2]; pv[t][1].y = ACC_[t][3];                         \
      ss2 = __builtin_elementwise_fma(pv[t][0], pv[t][0], ss2);                 \
      ss2 = __builtin_elementwise_fma(pv[t][1], pv[t][1], ss2);                 \
    }                                                                           \
    float ss = ss2.x + ss2.y;                                                   \
    ss += __shfl_xor(ss, 16);                                                   \
    ss += __shfl_xor(ss, 32);                                                   \
    const int j = (J0_) + n;                                                    \
    const float ew = (j <= (I_))                                                \
        ? __builtin_amdgcn_exp2f(sqrtf(ss) * 1.44269504f) : 0.f;                \
    L_ += ew;                                                                   \
    f32x2 ew2; ew2 = ew;                                                        \
    _Pragma("unroll")                                                           \
    for (int t = 0; t < 3; ++t) {                                               \
      O_[t][0] = __builtin_elementwise_fma(ew2, pv[t][0], O_[t][0]);            \
      O_[t][1] = __builtin_elementwise_fma(ew2, pv[t][1], O_[t][1]);            \
    } }

#define ACC_INIT(ACC_)                                                          \
  { ACC_[0] = b2q[0]; ACC_[1] = b2q[1]; ACC_[2] = b2q[2]; }

// one row, dual chunk streams (c, c+4) stepping 8, fused ks loop
#define PROCESS_ROW_DUAL(I_, ROW_, CSTART_, L_, O_)                             \
  { u32x4 avp[3];                                                               \
    _Pragma("unroll")                                                           \
    for (int ks = 0; ks < 3; ++ks)                                              \
      avp[ks] = *(const u32x4*)&Arow[(size_t)(ROW_) * TWO_D + ks * 32 + q8];    \
    const int nch = ((I_) + 16) >> 4;                                           \
    int c = (CSTART_);                                                          \
    const __half* __restrict__ Bp = Bbase + (size_t)((c << 4) + n) * TWO_D;     \
    u32x4 pbA[3], pbB[3];                                                       \
    if (c < nch) LOAD_PB(pbA, Bp);                                              \
    if (c + 4 < nch) LOAD_PB(pbB, Bp + 64 * TWO_D);                             \
    for (; c + 4 < nch; c += 8) {                                               \
      const bool pfA = (c + 8) < nch;                                           \
      const bool pfB = (c + 12) < nch;                                          \
      const __half* __restrict__ BpA = Bp + 128 * TWO_D;                        \
      const __half* __restrict__ BpB = Bp + 192 * TWO_D;                        \
      f32x4 accA[3], accB[3];                                                   \
      ACC_INIT(accA); ACC_INIT(accB);                                           \
      FUSED_KS(pbA, accA, pfA, BpA, true, pbB, accB, pfB, BpB);                 \
      CHUNK_EPI((c << 4), I_, accA, L_, O_);                                    \
      CHUNK_EPI(((c + 4) << 4), I_, accB, L_, O_);                              \
      Bp = BpA;                                                                 \
    }                                                                           \
    if (c < nch) {                                                              \
      f32x4 accA[3];                                                            \
      ACC_INIT(accA);                                                           \
      FUSED_KS(pbA, accA, false, Bp, false, pbB, accA, false, Bp);              \
      CHUNK_EPI((c << 4), I_, accA, L_, O_);                                    \
    } }

// reduce over n (16 lanes) and flush one row's partials to per-wave LDS slots
#define REDUCE_FLUSH(L_, O_, SEL_)                                              \
  { _Pragma("unroll")                                                           \
    for (int d = 1; d <= 8; d <<= 1) {                                          \
      L_ += __shfl_xor(L_, d);                                                  \
      _Pragma("unroll")                                                         \
      for (int t = 0; t < 3; ++t)                                               \
        _Pragma("unroll")                                                       \
        for (int r = 0; r < 2; ++r) {                                           \
          O_[t][r].x += __shfl_xor(O_[t][r].x, d);                              \
          O_[t][r].y += __shfl_xor(O_[t][r].y, d);                              \
        }                                                                       \
    }                                                                           \
    if (n == 0) {                                                               \
      _Pragma("unroll")                                                         \
      for (int t = 0; t < 3; ++t)                                               \
        _Pragma("unroll")                                                       \
        for (int r = 0; r < 2; ++r) {                                           \
          ored[wave][SEL_][t * 16 + 4 * q + 2 * r + 0] = O_[t][r].x;            \
          ored[wave][SEL_][t * 16 + 4 * q + 2 * r + 1] = O_[t][r].y;            \
        }                                                                       \
      if (q == 0) lred[wave][SEL_] = L_;                                        \
    } }

// Kernel 2: one block per (batch, row-PAIR (p, 511-p)); 33 chunks/block uniform;
// 1024 blocks co-resident; fused dual streams; f16 data path; W2T in LDS.
__global__ __launch_bounds__(256) void pair_softmax_kernel(
        const __half* __restrict__ Arow,
        const __half* __restrict__ Brow,
        const __half* __restrict__ W2T,
        const float* __restrict__ b2,
        float* __restrict__ out) {
    const int batch = blockIdx.x >> 8;        // 0..3
    const int pr = blockIdx.x & 255;          // 0..255
    const int iH = (NN - 1) - pr;             // 256..511
    const int iL = pr;                        // 0..255
    const int cH = (iH >> 4) + 1;             // 17..32; cH + cL = 33
    const int rowH = batch * NN + iH;
    const int rowL = batch * NN + iL;
    const __half* __restrict__ Bbase = Brow + (size_t)batch * NN * TWO_D;

    const int tid = threadIdx.x;
    const int wave = tid >> 6;                // 0..3
    const int lane = tid & 63;
    const int n = lane & 15;   // j-local (C/D col); also W2T A-frag row f-local
    const int q = lane >> 4;   // quad
    const int q8 = q * 8;

    __shared__ __align__(16) __half w2s[DD * W2P];   // padded W2T, ~10 KB
    __shared__ float lred[4][2];
    __shared__ float ored[4][2][DD];

    for (int idx = tid; idx < DD * TWO_D; idx += 256) {
        const int f = idx / TWO_D;
        const int k = idx - f * TWO_D;
        w2s[f * W2P + k] = W2T[idx];
    }
    __syncthreads();

    // b2 quad for this lane's C/D rows: f = t*16 + 4q + r  (folded into acc init)
    f32x4 b2q[3];
#pragma unroll
    for (int t = 0; t < 3; ++t)
        b2q[t] = *(const f32x4*)&b2[t * 16 + 4 * q];

    float lH = 0.f;
    f32x2 oH[3][2];
#pragma unroll
    for (int t = 0; t < 3; ++t)
#pragma unroll
        for (int r = 0; r < 2; ++r) oH[t][r] = 0.f;

    // Heavy row: chunks c ≡ wave (mod 4); flush immediately (frees regs)
    PROCESS_ROW_DUAL(iH, rowH, wave, lH, oH);
    REDUCE_FLUSH(lH, oH, 0);

    float lL = 0.f;
    f32x2 oL[3][2];
#pragma unroll
    for (int t = 0; t < 3; ++t)
#pragma unroll
        for (int r = 0; r < 2; ++r) oL[t][r] = 0.f;

    // Light row: global chunk index idx = cH + c ≡ wave (mod 4)
    const int cstartL = (wave + 128 - cH) & 3;
    PROCESS_ROW_DUAL(iL, rowL, cstartL, lL, oL);
    REDUCE_FLUSH(lL, oL, 1);

    __syncthreads();
    if (tid < 2 * DD) {
        const int sel = tid / DD;
        const int f = tid - sel * DD;
        float L = 0.f, O = 0.f;
#pragma unroll
        for (int wv = 0; wv < 4; ++wv) {
            L += lred[wv][sel];
            O += ored[wv][sel][f];
        }
        const int row = sel ? rowL : rowH;
        out[row * DD + f] = O / L;
    }
}

extern "C" void kernel_launch(void* const* d_in, const int* in_sizes, int n_in,
                              void* d_out, int out_size, void* d_ws, size_t ws_size,
                              hipStream_t stream) {
    const float* x  = (const float*)d_in[0];
    const float* W1 = (const float*)d_in[1];
    const float* b1 = (const float*)d_in[2];
    const float* W2 = (const float*)d_in[3];
    const float* b2 = (const float*)d_in[4];
    float* outp = (float*)d_out;

    __half* A   = (__half*)d_ws;            // 2048*96 f16
    __half* Bb  = A + ROWS * TWO_D;         // 2048*96 f16
    __half* W2T = Bb + ROWS * TWO_D;        // 48*96 f16

    precompute_kernel<<<ROWS / 4 + 1, 256, 0, stream>>>(x, W1, b1, W2, A, Bb, W2T);
    pair_softmax_kernel<<<1024, 256, 0, stream>>>(A, Bb, W2T, b2, outp);
}